// Round 1
// baseline (117.428 us; speedup 1.0000x reference)
//
#include <hip/hip_runtime.h>

// fastmax (degree-2 Taylor attention) for B=2,H=8,N=1024,D=64, fp32 in/out.
// o_i = sum_j (1 + s + 0.5 s^2) v_j / sum_j (1 + s + 0.5 s^2),
//   s_ij = q_i . k_j + q_i . rpe[i-j+N-1]
//
// 256 blocks = 16 bh * 16 i-tiles (BM=64 rows). 512 threads = 8 waves =
// 4 row-strips x 2 j-halves. Per j-tile (BN=64): stage K, V^T, rpe band to
// LDS as bf16; per wave: Toeplitz P-strip via MFMA -> wave-private LDS,
// QK^T MFMA, gather P diagonals, score in fp32, score->bf16 LDS, PV MFMA.
// fp32 accumulation everywhere; bf16 only as MFMA operands.

#define NSEQ 1024
#define DH   64
#define BM   64
#define BN   64

typedef short bf16x8 __attribute__((ext_vector_type(8)));
typedef float f32x4  __attribute__((ext_vector_type(4)));

__device__ __forceinline__ unsigned short f2bf(float x) {
    unsigned u = __float_as_uint(x);
    u += 0x7fffu + ((u >> 16) & 1u);          // round-to-nearest-even
    return (unsigned short)(u >> 16);
}
__device__ __forceinline__ float bf2f(unsigned short h) {
    return __uint_as_float(((unsigned)h) << 16);
}
__device__ __forceinline__ unsigned long long pack4(float4 x) {
    return (unsigned long long)f2bf(x.x)
         | ((unsigned long long)f2bf(x.y) << 16)
         | ((unsigned long long)f2bf(x.z) << 32)
         | ((unsigned long long)f2bf(x.w) << 48);
}

__global__ __launch_bounds__(512, 2)
void fastmax_kernel(const float* __restrict__ qg, const float* __restrict__ kg,
                    const float* __restrict__ vg, const float* __restrict__ rpe,
                    float* __restrict__ outg)
{
    // K tile: 64 rows x 64 bf16, row stride 128B, XOR-swizzled (conflict-free b128)
    __shared__ __align__(16) unsigned char ldsK[64 * 128];
    // RPE band: 128 rows x 64 bf16, swizzled
    __shared__ __align__(16) unsigned char ldsR[128 * 128];
    // V^T: [d=64][j=64] bf16, row stride 136B (68 elts, 8B-aligned reads)
    __shared__ __align__(16) unsigned char ldsVT[64 * 136];
    // per-wave Toeplitz P strip: 16 rows x 48 t-cols (128B row stride, swizzled)
    __shared__ __align__(16) unsigned char ldsP[8 * 16 * 128];
    // per-wave score strip: 16 rows x 32 cols bf16, row stride 80B (16B mult)
    __shared__ __align__(16) unsigned char ldsS[8 * 16 * 80];

    const int tid = threadIdx.x;
    const int w   = tid >> 6;       // wave 0..7
    const int l   = tid & 63;
    const int lr  = l & 15;
    const int lg  = l >> 4;
    const int ws  = w >> 1;         // row strip 0..3
    const int wj  = w & 1;          // j half 0..1

    const int bh = blockIdx.x >> 4;
    const int i0 = (blockIdx.x & 15) * BM;

    const float* qbh = qg + (size_t)bh * (NSEQ * DH);
    const float* kbh = kg + (size_t)bh * (NSEQ * DH);
    const float* vbh = vg + (size_t)bh * (NSEQ * DH);

    // Q A-fragments for this wave's 16-row strip (A: m=lane&15, k=(lane>>4)*8+e)
    bf16x8 qf[2];
    {
        const float* qrow = qbh + (size_t)(i0 + ws * 16 + lr) * DH + lg * 8;
        #pragma unroll
        for (int kc = 0; kc < 2; ++kc) {
            float4 a = *reinterpret_cast<const float4*>(qrow + kc * 32);
            float4 b = *reinterpret_cast<const float4*>(qrow + kc * 32 + 4);
            bf16x8 f;
            f[0] = (short)f2bf(a.x); f[1] = (short)f2bf(a.y);
            f[2] = (short)f2bf(a.z); f[3] = (short)f2bf(a.w);
            f[4] = (short)f2bf(b.x); f[5] = (short)f2bf(b.y);
            f[6] = (short)f2bf(b.z); f[7] = (short)f2bf(b.w);
            qf[kc] = f;
        }
    }

    f32x4 oacc[4];
    #pragma unroll
    for (int dt = 0; dt < 4; ++dt) oacc[dt] = (f32x4){0.f, 0.f, 0.f, 0.f};
    float dp[4] = {0.f, 0.f, 0.f, 0.f};

    unsigned char* myP = ldsP + w * (16 * 128);
    unsigned char* myS = ldsS + w * (16 * 80);
    const int t0w = ws * 16 - wj * 32 + 32;   // base t of this wave's P strip

    for (int jt = 0; jt < NSEQ / BN; ++jt) {
        const int j0  = jt * BN;
        const int rlo = i0 - j0 + 960;        // i0-j0+(N-1)-(BN-1), always >= 0

        __syncthreads();

        { // stage K tile (64x64 fp32 -> bf16, swizzled)
            const float4* src = reinterpret_cast<const float4*>(kbh + (size_t)j0 * DH);
            #pragma unroll
            for (int it = 0; it < 2; ++it) {
                int i = it * 512 + tid;
                float4 x = src[i];
                int row = i >> 4, colb = (i & 15) * 8;
                *reinterpret_cast<unsigned long long*>(
                    ldsK + ((row * 128 + colb) ^ ((row & 7) << 4))) = pack4(x);
            }
        }
        { // stage RPE band (rows rlo..rlo+127; row 127 may clamp, never gathered)
            #pragma unroll
            for (int it = 0; it < 4; ++it) {
                int i = it * 512 + tid;
                int row = i >> 4;
                int r = rlo + row; r = (r > 2 * NSEQ - 2) ? (2 * NSEQ - 2) : r;
                float4 x = reinterpret_cast<const float4*>(rpe + (size_t)r * DH)[i & 15];
                int colb = (i & 15) * 8;
                *reinterpret_cast<unsigned long long*>(
                    ldsR + ((row * 128 + colb) ^ ((row & 7) << 4))) = pack4(x);
            }
        }
        { // stage V^T (transpose during store; scalar b16 writes)
            const float4* src = reinterpret_cast<const float4*>(vbh + (size_t)j0 * DH);
            #pragma unroll
            for (int it = 0; it < 2; ++it) {
                int i = it * 512 + tid;
                float4 x = src[i];
                int j = i >> 4, d0 = (i & 15) * 4;
                unsigned char* p = ldsVT + j * 2;
                *reinterpret_cast<unsigned short*>(p + (d0 + 0) * 136) = f2bf(x.x);
                *reinterpret_cast<unsigned short*>(p + (d0 + 1) * 136) = f2bf(x.y);
                *reinterpret_cast<unsigned short*>(p + (d0 + 2) * 136) = f2bf(x.z);
                *reinterpret_cast<unsigned short*>(p + (d0 + 3) * 136) = f2bf(x.w);
            }
        }
        __syncthreads();

        // ---- P strip: P[row][t] = q_strip_row . rpe[rlo + t0w + t], t in [0,48)
        f32x4 pacc[3];
        #pragma unroll
        for (int ct = 0; ct < 3; ++ct) pacc[ct] = (f32x4){0.f, 0.f, 0.f, 0.f};
        #pragma unroll
        for (int kc = 0; kc < 2; ++kc) {
            #pragma unroll
            for (int ct = 0; ct < 3; ++ct) {
                int row = t0w + ct * 16 + lr;
                bf16x8 bfrag = *reinterpret_cast<const bf16x8*>(
                    ldsR + ((row * 128 + kc * 64 + lg * 16) ^ ((row & 7) << 4)));
                pacc[ct] = __builtin_amdgcn_mfma_f32_16x16x32_bf16(qf[kc], bfrag, pacc[ct], 0, 0, 0);
            }
        }
        #pragma unroll
        for (int ct = 0; ct < 3; ++ct) {
            #pragma unroll
            for (int r = 0; r < 4; ++r) {
                int row = lg * 4 + r;
                int tl  = ct * 16 + lr;
                *reinterpret_cast<unsigned short*>(
                    myP + ((row * 128 + tl * 2) ^ ((row & 7) << 4))) = f2bf(pacc[ct][r]);
            }
        }

        // ---- QK^T strip: rows 16, cols [wj*32, wj*32+32)
        f32x4 sacc[2];
        #pragma unroll
        for (int ct = 0; ct < 2; ++ct) sacc[ct] = (f32x4){0.f, 0.f, 0.f, 0.f};
        #pragma unroll
        for (int kc = 0; kc < 2; ++kc) {
            #pragma unroll
            for (int ct = 0; ct < 2; ++ct) {
                int row = wj * 32 + ct * 16 + lr;
                bf16x8 bfrag = *reinterpret_cast<const bf16x8*>(
                    ldsK + ((row * 128 + kc * 64 + lg * 16) ^ ((row & 7) << 4)));
                sacc[ct] = __builtin_amdgcn_mfma_f32_16x16x32_bf16(qf[kc], bfrag, sacc[ct], 0, 0, 0);
            }
        }

        // ---- score = 1 + s + 0.5 s^2 (fp32), gather Toeplitz P term
        #pragma unroll
        for (int ct = 0; ct < 2; ++ct) {
            #pragma unroll
            for (int r = 0; r < 4; ++r) {
                int row = lg * 4 + r;                 // strip-local i
                int tl  = row - ct * 16 - lr + 31;    // P strip col, in [0,47]
                float pval = bf2f(*reinterpret_cast<const unsigned short*>(
                    myP + ((row * 128 + tl * 2) ^ ((row & 7) << 4))));
                float s  = sacc[ct][r] + pval;
                float sc = fmaf(s, fmaf(0.5f, s, 1.0f), 1.0f);
                dp[r] += sc;
                int jjl = ct * 16 + lr;
                *reinterpret_cast<unsigned short*>(myS + row * 80 + jjl * 2) = f2bf(sc);
            }
        }

        // ---- O += score(16x32) * V(32x64)
        bf16x8 af = *reinterpret_cast<const bf16x8*>(myS + lr * 80 + lg * 16);
        #pragma unroll
        for (int dt = 0; dt < 4; ++dt) {
            const unsigned char* vp = ldsVT + (dt * 16 + lr) * 136 + wj * 64 + lg * 16;
            union { unsigned long long u[2]; bf16x8 v; } bb;
            bb.u[0] = *reinterpret_cast<const unsigned long long*>(vp);
            bb.u[1] = *reinterpret_cast<const unsigned long long*>(vp + 8);
            oacc[dt] = __builtin_amdgcn_mfma_f32_16x16x32_bf16(af, bb.v, oacc[dt], 0, 0, 0);
        }
    }

    // ---- epilogue: reduce denom across the 16 lanes of each row group
    #pragma unroll
    for (int r = 0; r < 4; ++r) {
        #pragma unroll
        for (int m = 1; m < 16; m <<= 1) dp[r] += __shfl_xor(dp[r], m, 64);
    }

    // combine the two j-half partials through LDS (reuse ldsR / ldsK)
    __syncthreads();
    float* ored = reinterpret_cast<float*>(ldsR);   // [strip][row][64] fp32
    float* dred = reinterpret_cast<float*>(ldsK);   // [strip][row] fp32
    if (wj == 1) {
        #pragma unroll
        for (int dt = 0; dt < 4; ++dt) {
            #pragma unroll
            for (int r = 0; r < 4; ++r) {
                int row = lg * 4 + r;
                ored[ws * 1024 + row * 64 + dt * 16 + lr] = oacc[dt][r];
            }
        }
        if (lr == 0) {
            #pragma unroll
            for (int r = 0; r < 4; ++r) dred[ws * 16 + lg * 4 + r] = dp[r];
        }
    }
    __syncthreads();
    if (wj == 0) {
        float* ob = outg + (size_t)bh * (NSEQ * DH) + (size_t)(i0 + ws * 16) * DH;
        float rd[4];
        #pragma unroll
        for (int r = 0; r < 4; ++r) {
            int row = lg * 4 + r;
            rd[r] = 1.0f / (dp[r] + dred[ws * 16 + row]);
        }
        #pragma unroll
        for (int dt = 0; dt < 4; ++dt) {
            #pragma unroll
            for (int r = 0; r < 4; ++r) {
                int row = lg * 4 + r;
                float num = oacc[dt][r] + ored[ws * 1024 + row * 64 + dt * 16 + lr];
                ob[row * DH + dt * 16 + lr] = num * rd[r];
            }
        }
    }
}

extern "C" void kernel_launch(void* const* d_in, const int* in_sizes, int n_in,
                              void* d_out, int out_size, void* d_ws, size_t ws_size,
                              hipStream_t stream) {
    const float* q   = (const float*)d_in[0];
    const float* k   = (const float*)d_in[1];
    const float* v   = (const float*)d_in[2];
    // d_in[3] = drop_noise, unused (dropout = 0)
    const float* rpe = (const float*)d_in[4];
    float* out = (float*)d_out;

    dim3 grid(256), block(512);
    hipLaunchKernelGGL(fastmax_kernel, grid, block, 0, stream, q, k, v, rpe, out);
}

// Round 6
// 109.334 us; speedup vs baseline: 1.0740x; 1.0740x over previous
//
#include <hip/hip_runtime.h>

// fastmax (degree-2 Taylor attention) for B=2,H=8,N=1024,D=64, fp32 in/out.
// o_i = sum_j (1 + s + 0.5 s^2) v_j / sum_j (1 + s + 0.5 s^2),
//   s_ij = q_i . k_j + q_i . rpe[i-j+N-1]
//
// Round 2 design (5th submit; rounds 2-5 were infra GPU-acquisition
// timeouts): j-split across blocks (JSPLIT, chosen from ws_size) to fix the
// 1-block/CU occupancy cap seen in round 1 (grid 256 -> 1024). Each wave
// writes partial numerator/denominator to d_ws; reduce kernel divides.

#define NSEQ 1024
#define DH   64
#define BM   64
#define BN   64
#define NBH  16
#define ROWS_TOTAL (NBH * NSEQ)            // 16384
#define NUM_ELEMS  ((size_t)ROWS_TOTAL * DH) // 1,048,576

typedef short bf16x8 __attribute__((ext_vector_type(8)));
typedef float f32x4  __attribute__((ext_vector_type(4)));

__device__ __forceinline__ unsigned short f2bf(float x) {
    unsigned u = __float_as_uint(x);
    u += 0x7fffu + ((u >> 16) & 1u);          // round-to-nearest-even
    return (unsigned short)(u >> 16);
}
__device__ __forceinline__ float bf2f(unsigned short h) {
    return __uint_as_float(((unsigned)h) << 16);
}
__device__ __forceinline__ unsigned long long pack4(float4 x) {
    return (unsigned long long)f2bf(x.x)
         | ((unsigned long long)f2bf(x.y) << 16)
         | ((unsigned long long)f2bf(x.z) << 32)
         | ((unsigned long long)f2bf(x.w) << 48);
}

template<int JSPLIT>
__global__ __launch_bounds__(512, 2)
void fastmax_kernel(const float* __restrict__ qg, const float* __restrict__ kg,
                    const float* __restrict__ vg, const float* __restrict__ rpe,
                    float* __restrict__ outg, float* __restrict__ wsbuf)
{
    // K tile: 64 rows x 64 bf16, row stride 128B, XOR-swizzled (conflict-free b128)
    __shared__ __align__(16) unsigned char ldsK[64 * 128];
    // RPE band: 128 rows x 64 bf16, swizzled
    __shared__ __align__(16) unsigned char ldsR[128 * 128];
    // V^T: [d=64][j=64] bf16, row stride 136B (8B-aligned b64 reads)
    __shared__ __align__(16) unsigned char ldsVT[64 * 136];
    // per-wave Toeplitz P strip: 16 rows x 48 t-cols (128B row stride, swizzled)
    __shared__ __align__(16) unsigned char ldsP[8 * 16 * 128];
    // per-wave score strip: 16 rows x 32 cols bf16, row stride 80B
    __shared__ __align__(16) unsigned char ldsS[8 * 16 * 80];

    const int tid = threadIdx.x;
    const int w   = tid >> 6;       // wave 0..7
    const int l   = tid & 63;
    const int lr  = l & 15;
    const int lg  = l >> 4;
    const int wst = w >> 1;         // row strip 0..3
    const int wj  = w & 1;          // j half 0..1

    const int b  = blockIdx.x;
    const int js = b % JSPLIT;
    const int it = (b / JSPLIT) & 15;
    const int bh = b / (JSPLIT * 16);
    const int i0 = it * BM;

    const float* qbh = qg + (size_t)bh * (NSEQ * DH);
    const float* kbh = kg + (size_t)bh * (NSEQ * DH);
    const float* vbh = vg + (size_t)bh * (NSEQ * DH);

    // Q A-fragments for this wave's 16-row strip (A: m=lane&15, k=(lane>>4)*8+e)
    bf16x8 qf[2];
    {
        const float* qrow = qbh + (size_t)(i0 + wst * 16 + lr) * DH + lg * 8;
        #pragma unroll
        for (int kc = 0; kc < 2; ++kc) {
            float4 a = *reinterpret_cast<const float4*>(qrow + kc * 32);
            float4 b4 = *reinterpret_cast<const float4*>(qrow + kc * 32 + 4);
            bf16x8 f;
            f[0] = (short)f2bf(a.x); f[1] = (short)f2bf(a.y);
            f[2] = (short)f2bf(a.z); f[3] = (short)f2bf(a.w);
            f[4] = (short)f2bf(b4.x); f[5] = (short)f2bf(b4.y);
            f[6] = (short)f2bf(b4.z); f[7] = (short)f2bf(b4.w);
            qf[kc] = f;
        }
    }

    f32x4 oacc[4];
    #pragma unroll
    for (int dt = 0; dt < 4; ++dt) oacc[dt] = (f32x4){0.f, 0.f, 0.f, 0.f};
    float dp[4] = {0.f, 0.f, 0.f, 0.f};

    unsigned char* myP = ldsP + w * (16 * 128);
    unsigned char* myS = ldsS + w * (16 * 80);
    const int t0w = wst * 16 - wj * 32 + 32;   // base t of this wave's P strip

    constexpr int NJT = (NSEQ / BN) / JSPLIT;
    for (int jt = js * NJT; jt < (js + 1) * NJT; ++jt) {
        const int j0  = jt * BN;
        const int rlo = i0 - j0 + 960;        // always >= 0

        __syncthreads();

        { // stage K tile (64x64 fp32 -> bf16, swizzled)
            const float4* src = reinterpret_cast<const float4*>(kbh + (size_t)j0 * DH);
            #pragma unroll
            for (int itr = 0; itr < 2; ++itr) {
                int i = itr * 512 + tid;
                float4 x = src[i];
                int row = i >> 4, colb = (i & 15) * 8;
                *reinterpret_cast<unsigned long long*>(
                    ldsK + ((row * 128 + colb) ^ ((row & 7) << 4))) = pack4(x);
            }
        }
        { // stage RPE band (rows rlo..rlo+127; row 127 may clamp, never gathered)
            #pragma unroll
            for (int itr = 0; itr < 4; ++itr) {
                int i = itr * 512 + tid;
                int row = i >> 4;
                int r = rlo + row; r = (r > 2 * NSEQ - 2) ? (2 * NSEQ - 2) : r;
                float4 x = reinterpret_cast<const float4*>(rpe + (size_t)r * DH)[i & 15];
                int colb = (i & 15) * 8;
                *reinterpret_cast<unsigned long long*>(
                    ldsR + ((row * 128 + colb) ^ ((row & 7) << 4))) = pack4(x);
            }
        }
        { // stage V^T (transpose during store; scalar b16 writes)
            const float4* src = reinterpret_cast<const float4*>(vbh + (size_t)j0 * DH);
            #pragma unroll
            for (int itr = 0; itr < 2; ++itr) {
                int i = itr * 512 + tid;
                float4 x = src[i];
                int j = i >> 4, d0 = (i & 15) * 4;
                unsigned char* p = ldsVT + j * 2;
                *reinterpret_cast<unsigned short*>(p + (d0 + 0) * 136) = f2bf(x.x);
                *reinterpret_cast<unsigned short*>(p + (d0 + 1) * 136) = f2bf(x.y);
                *reinterpret_cast<unsigned short*>(p + (d0 + 2) * 136) = f2bf(x.z);
                *reinterpret_cast<unsigned short*>(p + (d0 + 3) * 136) = f2bf(x.w);
            }
        }
        __syncthreads();

        // ---- P strip: P[row][t] = q_strip_row . rpe[rlo + t0w + t], t in [0,48)
        f32x4 pacc[3];
        #pragma unroll
        for (int ct = 0; ct < 3; ++ct) pacc[ct] = (f32x4){0.f, 0.f, 0.f, 0.f};
        #pragma unroll
        for (int kc = 0; kc < 2; ++kc) {
            #pragma unroll
            for (int ct = 0; ct < 3; ++ct) {
                int row = t0w + ct * 16 + lr;
                bf16x8 bfrag = *reinterpret_cast<const bf16x8*>(
                    ldsR + ((row * 128 + kc * 64 + lg * 16) ^ ((row & 7) << 4)));
                pacc[ct] = __builtin_amdgcn_mfma_f32_16x16x32_bf16(qf[kc], bfrag, pacc[ct], 0, 0, 0);
            }
        }
        #pragma unroll
        for (int ct = 0; ct < 3; ++ct) {
            #pragma unroll
            for (int r = 0; r < 4; ++r) {
                int row = lg * 4 + r;
                int tl  = ct * 16 + lr;
                *reinterpret_cast<unsigned short*>(
                    myP + ((row * 128 + tl * 2) ^ ((row & 7) << 4))) = f2bf(pacc[ct][r]);
            }
        }

        // ---- QK^T strip: rows 16, cols [wj*32, wj*32+32)
        f32x4 sacc[2];
        #pragma unroll
        for (int ct = 0; ct < 2; ++ct) sacc[ct] = (f32x4){0.f, 0.f, 0.f, 0.f};
        #pragma unroll
        for (int kc = 0; kc < 2; ++kc) {
            #pragma unroll
            for (int ct = 0; ct < 2; ++ct) {
                int row = wj * 32 + ct * 16 + lr;
                bf16x8 bfrag = *reinterpret_cast<const bf16x8*>(
                    ldsK + ((row * 128 + kc * 64 + lg * 16) ^ ((row & 7) << 4)));
                sacc[ct] = __builtin_amdgcn_mfma_f32_16x16x32_bf16(qf[kc], bfrag, sacc[ct], 0, 0, 0);
            }
        }

        // ---- score = 1 + s + 0.5 s^2 (fp32), gather Toeplitz P term
        #pragma unroll
        for (int ct = 0; ct < 2; ++ct) {
            #pragma unroll
            for (int r = 0; r < 4; ++r) {
                int row = lg * 4 + r;                 // strip-local i
                int tl  = row - ct * 16 - lr + 31;    // P strip col, in [0,47]
                float pval = bf2f(*reinterpret_cast<const unsigned short*>(
                    myP + ((row * 128 + tl * 2) ^ ((row & 7) << 4))));
                float s  = sacc[ct][r] + pval;
                float sc = fmaf(s, fmaf(0.5f, s, 1.0f), 1.0f);
                dp[r] += sc;
                int jjl = ct * 16 + lr;
                *reinterpret_cast<unsigned short*>(myS + row * 80 + jjl * 2) = f2bf(sc);
            }
        }

        // ---- O += score(16x32) * V(32x64)
        bf16x8 af = *reinterpret_cast<const bf16x8*>(myS + lr * 80 + lg * 16);
        #pragma unroll
        for (int dt = 0; dt < 4; ++dt) {
            const unsigned char* vp = ldsVT + (dt * 16 + lr) * 136 + wj * 64 + lg * 16;
            union { unsigned long long u[2]; bf16x8 v; } bb;
            bb.u[0] = *reinterpret_cast<const unsigned long long*>(vp);
            bb.u[1] = *reinterpret_cast<const unsigned long long*>(vp + 8);
            oacc[dt] = __builtin_amdgcn_mfma_f32_16x16x32_bf16(af, bb.v, oacc[dt], 0, 0, 0);
        }
    }

    // ---- denom: reduce across the 16 lanes of each row group
    #pragma unroll
    for (int r = 0; r < 4; ++r) {
        #pragma unroll
        for (int m = 1; m < 16; m <<= 1) dp[r] += __shfl_xor(dp[r], m, 64);
    }

    if constexpr (JSPLIT == 1) {
        // combine the two j-half partials through LDS (reuse ldsR / ldsK)
        __syncthreads();
        float* ored = reinterpret_cast<float*>(ldsR);   // [strip][row][64] fp32
        float* dred = reinterpret_cast<float*>(ldsK);   // [strip][row] fp32
        if (wj == 1) {
            #pragma unroll
            for (int dt = 0; dt < 4; ++dt) {
                #pragma unroll
                for (int r = 0; r < 4; ++r) {
                    int row = lg * 4 + r;
                    ored[wst * 1024 + row * 64 + dt * 16 + lr] = oacc[dt][r];
                }
            }
            if (lr == 0) {
                #pragma unroll
                for (int r = 0; r < 4; ++r) dred[wst * 16 + lg * 4 + r] = dp[r];
            }
        }
        __syncthreads();
        if (wj == 0) {
            float* ob = outg + (size_t)bh * (NSEQ * DH) + (size_t)(i0 + wst * 16) * DH;
            float rd[4];
            #pragma unroll
            for (int r = 0; r < 4; ++r) {
                int row = lg * 4 + r;
                rd[r] = 1.0f / (dp[r] + dred[wst * 16 + row]);
            }
            #pragma unroll
            for (int dt = 0; dt < 4; ++dt) {
                #pragma unroll
                for (int r = 0; r < 4; ++r) {
                    int row = lg * 4 + r;
                    float num = oacc[dt][r] + ored[wst * 1024 + row * 64 + dt * 16 + lr];
                    ob[row * DH + dt * 16 + lr] = num * rd[r];
                }
            }
        }
    } else {
        // each wave writes its own partial (j-half + j-split => 2*JSPLIT partials)
        const int js2  = js * 2 + wj;                 // 0 .. 2*JSPLIT-1
        const int rowg = bh * NSEQ + i0 + wst * 16;   // global row of strip base
        float* nw = wsbuf + (size_t)js2 * NUM_ELEMS + (size_t)rowg * DH;
        #pragma unroll
        for (int dt = 0; dt < 4; ++dt) {
            #pragma unroll
            for (int r = 0; r < 4; ++r) {
                nw[(lg * 4 + r) * DH + dt * 16 + lr] = oacc[dt][r];
            }
        }
        float* dw = wsbuf + (size_t)(2 * JSPLIT) * NUM_ELEMS + (size_t)js2 * ROWS_TOTAL + rowg;
        if (lr == 0) {
            #pragma unroll
            for (int r = 0; r < 4; ++r) dw[lg * 4 + r] = dp[r];
        }
    }
}

template<int NP>
__global__ __launch_bounds__(256)
void reduce_kernel(const float* __restrict__ wsbuf, float* __restrict__ outg)
{
    const size_t idx  = (size_t)blockIdx.x * 256 + threadIdx.x;
    const size_t flat = idx * 4;                  // 4 floats per thread
    const int row = (int)(flat >> 6);
    const float* dbase = wsbuf + (size_t)NP * NUM_ELEMS;

    float4 acc = make_float4(0.f, 0.f, 0.f, 0.f);
    float den = 0.f;
    #pragma unroll
    for (int p = 0; p < NP; ++p) {
        float4 x = *reinterpret_cast<const float4*>(wsbuf + (size_t)p * NUM_ELEMS + flat);
        acc.x += x.x; acc.y += x.y; acc.z += x.z; acc.w += x.w;
        den += dbase[(size_t)p * ROWS_TOTAL + row];
    }
    float rdi = 1.0f / den;
    acc.x *= rdi; acc.y *= rdi; acc.z *= rdi; acc.w *= rdi;
    *reinterpret_cast<float4*>(outg + flat) = acc;
}

extern "C" void kernel_launch(void* const* d_in, const int* in_sizes, int n_in,
                              void* d_out, int out_size, void* d_ws, size_t ws_size,
                              hipStream_t stream) {
    const float* q   = (const float*)d_in[0];
    const float* k   = (const float*)d_in[1];
    const float* v   = (const float*)d_in[2];
    // d_in[3] = drop_noise, unused (dropout = 0)
    const float* rpe = (const float*)d_in[4];
    float* out = (float*)d_out;
    float* wsb = (float*)d_ws;

    auto need = [](int jsplit) -> size_t {
        return ((size_t)(2 * jsplit) * NUM_ELEMS + (size_t)(2 * jsplit) * ROWS_TOTAL)
               * sizeof(float);
    };

    if (ws_size >= need(4)) {
        hipLaunchKernelGGL((fastmax_kernel<4>), dim3(256 * 4), dim3(512), 0, stream,
                           q, k, v, rpe, out, wsb);
        hipLaunchKernelGGL((reduce_kernel<8>), dim3(1024), dim3(256), 0, stream, wsb, out);
    } else if (ws_size >= need(2)) {
        hipLaunchKernelGGL((fastmax_kernel<2>), dim3(256 * 2), dim3(512), 0, stream,
                           q, k, v, rpe, out, wsb);
        hipLaunchKernelGGL((reduce_kernel<4>), dim3(1024), dim3(256), 0, stream, wsb, out);
    } else {
        hipLaunchKernelGGL((fastmax_kernel<1>), dim3(256), dim3(512), 0, stream,
                           q, k, v, rpe, out, wsb);
    }
}

// Round 9
// 102.514 us; speedup vs baseline: 1.1455x; 1.0665x over previous
//
#include <hip/hip_runtime.h>
#include <hip/hip_bf16.h>

// fastmax (degree-2 Taylor attention) for B=2,H=8,N=1024,D=64, fp32 in/out.
// o_i = sum_j (1 + s + 0.5 s^2) v_j / sum_j (1 + s + 0.5 s^2),
//   s_ij = q_i.k_j + q_i.rpe[i-j+N-1]
//
// Round 9 = round-6 passing kernel + EXACTLY two changes:
//  (a) native bf16 casts (__float2bfloat16 -> v_cvt_pk_bf16_f32)
//  (b) P-strip in registers + ds_bpermute diagonal gather (ldsP deleted)
// Everything else byte-identical to round 6: single-buffer 2-barrier staging,
// S stride 80, V^T stride 136 unswizzled, 8-partial epilogue + reduce<8>,
// __launch_bounds__(512,2).

#define NSEQ 1024
#define DH   64
#define BM   64
#define BN   64
#define NBH  16
#define ROWS_TOTAL (NBH * NSEQ)              // 16384
#define NUM_ELEMS  ((size_t)ROWS_TOTAL * DH) // 1,048,576

typedef short bf16x8 __attribute__((ext_vector_type(8)));
typedef float f32x4  __attribute__((ext_vector_type(4)));

__device__ __forceinline__ unsigned short f2bf(float x) {
    return __builtin_bit_cast(unsigned short, __float2bfloat16(x));
}
__device__ __forceinline__ unsigned pack2(float lo, float hi) {
    return (unsigned)f2bf(lo) | ((unsigned)f2bf(hi) << 16);
}
__device__ __forceinline__ unsigned long long pack4(float4 x) {
    unsigned lo = pack2(x.x, x.y), hi = pack2(x.z, x.w);
    return (unsigned long long)lo | ((unsigned long long)hi << 32);
}

template<int JSPLIT>
__global__ __launch_bounds__(512, 2)
void fastmax_kernel(const float* __restrict__ qg, const float* __restrict__ kg,
                    const float* __restrict__ vg, const float* __restrict__ rpe,
                    float* __restrict__ outg, float* __restrict__ wsbuf)
{
    // K tile: 64 rows x 64 bf16, row stride 128B, XOR-swizzled
    __shared__ __align__(16) unsigned char ldsK[64 * 128];
    // RPE band: 128 rows x 64 bf16, swizzled
    __shared__ __align__(16) unsigned char ldsR[128 * 128];
    // V^T: [d=64][j=64] bf16, row stride 136B
    __shared__ __align__(16) unsigned char ldsVT[64 * 136];
    // per-wave score strip: 16 rows x 32 cols bf16, row stride 80B
    __shared__ __align__(16) unsigned char ldsS[8 * 16 * 80];

    const int tid = threadIdx.x;
    const int w   = tid >> 6;       // wave 0..7
    const int l   = tid & 63;
    const int lr  = l & 15;
    const int lg  = l >> 4;
    const int wst = w >> 1;         // row strip 0..3
    const int wj  = w & 1;          // j half 0..1

    const int b  = blockIdx.x;
    const int js = b % JSPLIT;
    const int it = (b / JSPLIT) & 15;
    const int bh = b / (JSPLIT * 16);
    const int i0 = it * BM;

    const float* qbh = qg + (size_t)bh * (NSEQ * DH);
    const float* kbh = kg + (size_t)bh * (NSEQ * DH);
    const float* vbh = vg + (size_t)bh * (NSEQ * DH);

    // Q A-fragments (A: m=lane&15, k=(lane>>4)*8+e)
    bf16x8 qf[2];
    {
        const float* qrow = qbh + (size_t)(i0 + wst * 16 + lr) * DH + lg * 8;
        #pragma unroll
        for (int kc = 0; kc < 2; ++kc) {
            float4 a  = *reinterpret_cast<const float4*>(qrow + kc * 32);
            float4 b4 = *reinterpret_cast<const float4*>(qrow + kc * 32 + 4);
            bf16x8 f;
            f[0] = (short)f2bf(a.x);  f[1] = (short)f2bf(a.y);
            f[2] = (short)f2bf(a.z);  f[3] = (short)f2bf(a.w);
            f[4] = (short)f2bf(b4.x); f[5] = (short)f2bf(b4.y);
            f[6] = (short)f2bf(b4.z); f[7] = (short)f2bf(b4.w);
            qf[kc] = f;
        }
    }

    f32x4 oacc[4];
    #pragma unroll
    for (int dt = 0; dt < 4; ++dt) oacc[dt] = (f32x4){0.f, 0.f, 0.f, 0.f};
    float dp[4] = {0.f, 0.f, 0.f, 0.f};

    unsigned char* myS = ldsS + w * (16 * 80);
    const int t0w = wst * 16 - wj * 32 + 32;   // base band index of wave's P strip

    constexpr int NJT = (NSEQ / BN) / JSPLIT;
    for (int jt = js * NJT; jt < (js + 1) * NJT; ++jt) {
        const int j0  = jt * BN;
        const int rlo = i0 - j0 + 960;        // always >= 0

        __syncthreads();

        { // stage K tile (64x64 fp32 -> bf16, swizzled)
            const float4* src = reinterpret_cast<const float4*>(kbh + (size_t)j0 * DH);
            #pragma unroll
            for (int itr = 0; itr < 2; ++itr) {
                int i = itr * 512 + tid;
                float4 x = src[i];
                int row = i >> 4, colb = (i & 15) * 8;
                *reinterpret_cast<unsigned long long*>(
                    ldsK + ((row * 128 + colb) ^ ((row & 7) << 4))) = pack4(x);
            }
        }
        { // stage RPE band (rows rlo..rlo+127; clamped row feeds only unused t=47)
            #pragma unroll
            for (int itr = 0; itr < 4; ++itr) {
                int i = itr * 512 + tid;
                int row = i >> 4;
                int r = rlo + row; if (r > 2 * NSEQ - 2) r = 2 * NSEQ - 2;
                float4 x = reinterpret_cast<const float4*>(rpe)[r * 16 + (i & 15)];
                int colb = (i & 15) * 8;
                *reinterpret_cast<unsigned long long*>(
                    ldsR + ((row * 128 + colb) ^ ((row & 7) << 4))) = pack4(x);
            }
        }
        { // stage V^T (transpose during store; scalar b16 writes)
            const float4* src = reinterpret_cast<const float4*>(vbh + (size_t)j0 * DH);
            #pragma unroll
            for (int itr = 0; itr < 2; ++itr) {
                int i = itr * 512 + tid;
                float4 x = src[i];
                int j = i >> 4, d0 = (i & 15) * 4;
                unsigned char* p = ldsVT + j * 2;
                *reinterpret_cast<unsigned short*>(p + (d0 + 0) * 136) = f2bf(x.x);
                *reinterpret_cast<unsigned short*>(p + (d0 + 1) * 136) = f2bf(x.y);
                *reinterpret_cast<unsigned short*>(p + (d0 + 2) * 136) = f2bf(x.z);
                *reinterpret_cast<unsigned short*>(p + (d0 + 3) * 136) = f2bf(x.w);
            }
        }
        __syncthreads();

        // ---- P strip (in regs): P[m][t] = q_m . rpe[rlo + t0w + t], t in [0,48)
        f32x4 pacc[3];
        #pragma unroll
        for (int ct = 0; ct < 3; ++ct) pacc[ct] = (f32x4){0.f, 0.f, 0.f, 0.f};
        #pragma unroll
        for (int kc = 0; kc < 2; ++kc) {
            #pragma unroll
            for (int ct = 0; ct < 3; ++ct) {
                int row = t0w + ct * 16 + lr;
                bf16x8 bfrag = *reinterpret_cast<const bf16x8*>(
                    ldsR + ((row * 128 + kc * 64 + lg * 16) ^ ((row & 7) << 4)));
                pacc[ct] = __builtin_amdgcn_mfma_f32_16x16x32_bf16(qf[kc], bfrag, pacc[ct], 0, 0, 0);
            }
        }

        // ---- QK^T strip: rows 16 (m), cols [wj*32, wj*32+32)
        f32x4 sacc[2];
        #pragma unroll
        for (int ct = 0; ct < 2; ++ct) sacc[ct] = (f32x4){0.f, 0.f, 0.f, 0.f};
        #pragma unroll
        for (int kc = 0; kc < 2; ++kc) {
            #pragma unroll
            for (int ct = 0; ct < 2; ++ct) {
                int row = wj * 32 + ct * 16 + lr;
                bf16x8 bfrag = *reinterpret_cast<const bf16x8*>(
                    ldsK + ((row * 128 + kc * 64 + lg * 16) ^ ((row & 7) << 4)));
                sacc[ct] = __builtin_amdgcn_mfma_f32_16x16x32_bf16(qf[kc], bfrag, sacc[ct], 0, 0, 0);
            }
        }

        // ---- gather Toeplitz P term via bpermute, score, write S (bf16)
        // Need P[m][t], t = 31 + m - (ct_s*16 + lr). P[m][t] = pacc[t>>4][m&3]
        // at lane (same lg group, lane (t&15) = (m-lr+15)&15).
        // ct_s=0 -> (m>lr ? pacc2 : pacc1); ct_s=1 -> (m>lr ? pacc1 : pacc0).
        #pragma unroll
        for (int r = 0; r < 4; ++r) {
            int m = lg * 4 + r;
            int idx = ((l & 48) + ((m - lr + 15) & 15)) << 2;
            int g0 = __builtin_amdgcn_ds_bpermute(idx, __float_as_int(pacc[0][r]));
            int g1 = __builtin_amdgcn_ds_bpermute(idx, __float_as_int(pacc[1][r]));
            int g2 = __builtin_amdgcn_ds_bpermute(idx, __float_as_int(pacc[2][r]));
            bool hi = (m > lr);
            float p0 = __int_as_float(hi ? g2 : g1);   // ct_s = 0
            float p1 = __int_as_float(hi ? g1 : g0);   // ct_s = 1
            float s0 = sacc[0][r] + p0;
            float c0 = fmaf(s0, fmaf(0.5f, s0, 1.0f), 1.0f);
            dp[r] += c0;
            *reinterpret_cast<unsigned short*>(myS + m * 80 + lr * 2) = f2bf(c0);
            float s1 = sacc[1][r] + p1;
            float c1 = fmaf(s1, fmaf(0.5f, s1, 1.0f), 1.0f);
            dp[r] += c1;
            *reinterpret_cast<unsigned short*>(myS + m * 80 + 32 + lr * 2) = f2bf(c1);
        }

        // ---- O += score(16x32) * V(32x64)
        bf16x8 af = *reinterpret_cast<const bf16x8*>(myS + lr * 80 + lg * 16);
        #pragma unroll
        for (int dt = 0; dt < 4; ++dt) {
            const unsigned char* vp = ldsVT + (dt * 16 + lr) * 136 + wj * 64 + lg * 16;
            union { unsigned long long u[2]; bf16x8 v; } bb;
            bb.u[0] = *reinterpret_cast<const unsigned long long*>(vp);
            bb.u[1] = *reinterpret_cast<const unsigned long long*>(vp + 8);
            oacc[dt] = __builtin_amdgcn_mfma_f32_16x16x32_bf16(af, bb.v, oacc[dt], 0, 0, 0);
        }
    }

    // ---- denom: reduce across the 16 lanes of each row group
    #pragma unroll
    for (int r = 0; r < 4; ++r) {
        #pragma unroll
        for (int m = 1; m < 16; m <<= 1) dp[r] += __shfl_xor(dp[r], m, 64);
    }

    if constexpr (JSPLIT == 1) {
        // combine the two j-half partials through LDS (reuse ldsR / ldsK)
        __syncthreads();
        float* ored = reinterpret_cast<float*>(ldsR);   // [strip][row][64] fp32
        float* dred = reinterpret_cast<float*>(ldsK);   // [strip][row] fp32
        if (wj == 1) {
            #pragma unroll
            for (int dt = 0; dt < 4; ++dt) {
                #pragma unroll
                for (int r = 0; r < 4; ++r) {
                    int row = lg * 4 + r;
                    ored[wst * 1024 + row * 64 + dt * 16 + lr] = oacc[dt][r];
                }
            }
            if (lr == 0) {
                #pragma unroll
                for (int r = 0; r < 4; ++r) dred[wst * 16 + lg * 4 + r] = dp[r];
            }
        }
        __syncthreads();
        if (wj == 0) {
            float* ob = outg + (size_t)bh * (NSEQ * DH) + (size_t)(i0 + wst * 16) * DH;
            float rd[4];
            #pragma unroll
            for (int r = 0; r < 4; ++r) {
                int row = lg * 4 + r;
                rd[r] = 1.0f / (dp[r] + dred[wst * 16 + row]);
            }
            #pragma unroll
            for (int dt = 0; dt < 4; ++dt) {
                #pragma unroll
                for (int r = 0; r < 4; ++r) {
                    int row = lg * 4 + r;
                    float num = oacc[dt][r] + ored[wst * 1024 + row * 64 + dt * 16 + lr];
                    ob[row * DH + dt * 16 + lr] = num * rd[r];
                }
            }
        }
    } else {
        // each wave writes its own partial (j-half + j-split => 2*JSPLIT partials)
        const int js2  = js * 2 + wj;                 // 0 .. 2*JSPLIT-1
        const int rowg = bh * NSEQ + i0 + wst * 16;   // global row of strip base
        float* nw = wsbuf + (size_t)js2 * NUM_ELEMS + (size_t)rowg * DH;
        #pragma unroll
        for (int dt = 0; dt < 4; ++dt) {
            #pragma unroll
            for (int r = 0; r < 4; ++r) {
                nw[(lg * 4 + r) * DH + dt * 16 + lr] = oacc[dt][r];
            }
        }
        float* dw = wsbuf + (size_t)(2 * JSPLIT) * NUM_ELEMS + (size_t)js2 * ROWS_TOTAL + rowg;
        if (lr == 0) {
            #pragma unroll
            for (int r = 0; r < 4; ++r) dw[lg * 4 + r] = dp[r];
        }
    }
}

template<int NP>
__global__ __launch_bounds__(256)
void reduce_kernel(const float* __restrict__ wsbuf, float* __restrict__ outg)
{
    const size_t idx  = (size_t)blockIdx.x * 256 + threadIdx.x;
    const size_t flat = idx * 4;                  // 4 floats per thread
    const int row = (int)(flat >> 6);
    const float* dbase = wsbuf + (size_t)NP * NUM_ELEMS;

    float4 acc = make_float4(0.f, 0.f, 0.f, 0.f);
    float den = 0.f;
    #pragma unroll
    for (int p = 0; p < NP; ++p) {
        float4 x = *reinterpret_cast<const float4*>(wsbuf + (size_t)p * NUM_ELEMS + flat);
        acc.x += x.x; acc.y += x.y; acc.z += x.z; acc.w += x.w;
        den += dbase[(size_t)p * ROWS_TOTAL + row];
    }
    float rdi = 1.0f / den;
    acc.x *= rdi; acc.y *= rdi; acc.z *= rdi; acc.w *= rdi;
    *reinterpret_cast<float4*>(outg + flat) = acc;
}

extern "C" void kernel_launch(void* const* d_in, const int* in_sizes, int n_in,
                              void* d_out, int out_size, void* d_ws, size_t ws_size,
                              hipStream_t stream) {
    const float* q   = (const float*)d_in[0];
    const float* k   = (const float*)d_in[1];
    const float* v   = (const float*)d_in[2];
    // d_in[3] = drop_noise, unused (dropout = 0)
    const float* rpe = (const float*)d_in[4];
    float* out = (float*)d_out;
    float* wsb = (float*)d_ws;

    auto need = [](int jsplit) -> size_t {
        return ((size_t)(2 * jsplit) * NUM_ELEMS + (size_t)(2 * jsplit) * ROWS_TOTAL)
               * sizeof(float);
    };

    if (ws_size >= need(4)) {
        hipLaunchKernelGGL((fastmax_kernel<4>), dim3(256 * 4), dim3(512), 0, stream,
                           q, k, v, rpe, out, wsb);
        hipLaunchKernelGGL((reduce_kernel<8>), dim3(1024), dim3(256), 0, stream, wsb, out);
    } else if (ws_size >= need(2)) {
        hipLaunchKernelGGL((fastmax_kernel<2>), dim3(256 * 2), dim3(512), 0, stream,
                           q, k, v, rpe, out, wsb);
        hipLaunchKernelGGL((reduce_kernel<4>), dim3(1024), dim3(256), 0, stream, wsb, out);
    } else {
        hipLaunchKernelGGL((fastmax_kernel<1>), dim3(256), dim3(512), 0, stream,
                           q, k, v, rpe, out, wsb);
    }
}